// Round 10
// baseline (106.465 us; speedup 1.0000x reference)
//
#include <hip/hip_runtime.h>
#include <hip/hip_bf16.h>

#define D_ 64
#define S_ 2048
#define B_ 16
#define QT 64
#define KVT 128

typedef short short8 __attribute__((ext_vector_type(8)));
typedef float floatx4 __attribute__((ext_vector_type(4)));
typedef unsigned uint4v __attribute__((ext_vector_type(4)));

// exp(s/sqrt(2048)) == exp2(s * SC2); SC2 is pre-folded into the K pack.
#define SC2 (1.4426950408889634f / 45.254833995939045f)

__device__ __forceinline__ unsigned short f2bf(float f) {
  unsigned u = __builtin_bit_cast(unsigned, f);
  u += 0x7fffu + ((u >> 16) & 1u);   // round-to-nearest-even
  return (unsigned short)(u >> 16);
}

// two f32 -> packed bf16x2 (RNE), compiler-blessed path (emits
// v_cvt_pk_bf16_f32). __hip_bfloat162 is not trivially copyable -> memcpy.
__device__ __forceinline__ unsigned pk2(float a, float b) {
  __hip_bfloat162 h = __float22bfloat162_rn(float2{a, b});
  unsigned r;
  __builtin_memcpy(&r, &h, sizeof(r));
  return r;
}

// ---------------------------------------------------------------------------
// FRAGMENT-ORDERED layouts (so attn's loads are lane-contiguous):
//   Q/K: per b, 128 row-tiles (16 rows x 64 d). Element (row,d):
//        rb=row>>4, ln=row&15, ks=d>>5, g=(d>>3)&3, j=d&7
//        addr = (b*128+rb)*1024 + ks*512 + (g*16+ln)*8 + j
//   V (k-PERMUTED for x32 PV): per b, 64 kv-chunks (32 kv) x 4 dblk.
//        Lane l=(g,ln), elem e: d = dblk*16+ln, kv = c32*32 + perm(g,e),
//        perm(g,e) = e<4 ? 4g+e : 16+4g+(e-4)
//        addr = ((b*64+c32)*4+dblk)*512 + l*8 + e
// ---------------------------------------------------------------------------
__global__ __launch_bounds__(256) void pack_all(const float* __restrict__ Q,
                                                const float* __restrict__ K,
                                                const float* __restrict__ V,
                                                unsigned short* __restrict__ Qp,
                                                unsigned short* __restrict__ Kp,
                                                unsigned short* __restrict__ Vt) {
  __shared__ __align__(16) unsigned short tile[256][72];
  const int t = threadIdx.x;
  const int bid = blockIdx.x;
  if (bid < 256) {
    const bool isK = bid >= 128;
    const float* src = isK ? K : Q;
    unsigned short* dst = isK ? Kp : Qp;
    const float scale = isK ? SC2 : 1.0f;
    const int rb = bid & 127;
    const int s0 = rb * 16;
#pragma unroll
    for (int i = 0; i < 16; i++) {
      int j = i * 256 + t;
      int d = j >> 6;
      int sb4 = (j & 63) * 4;
      const float4 v = *(const float4*)(src + (size_t)d * (S_ * B_) + s0 * B_ + sb4);
      float vv[4] = {v.x, v.y, v.z, v.w};
#pragma unroll
      for (int k = 0; k < 4; k++) {
        int sb = sb4 + k;                    // si = sb>>4, b = sb&15
        tile[(sb & 15) * 16 + (sb >> 4)][d] = f2bf(vv[k] * scale);
      }
    }
    __syncthreads();
#pragma unroll
    for (int i = 0; i < 8; i++) {
      int j = i * 256 + t;
      int r = j >> 3, c = j & 7;
      int b = r >> 4, si = r & 15;
      uint4 v = *(const uint4*)(&tile[r][c * 8]);
      // frag order: ks=c>>2, g=c&3, ln=si, j=0..7 contiguous -> one uint4
      *(uint4*)(dst + (((size_t)(b * 128 + rb)) << 10) + ((c >> 2) << 9) +
                (((c & 3) * 16 + si) << 3)) = v;
    }
  } else {
    const int vb = bid - 256;
    const int s0 = (vb & 31) * 64;           // 64 kv per block
    const int d0 = (vb >> 5) * 16;
    const int dblk = vb >> 5;
#pragma unroll
    for (int i = 0; i < 16; i++) {
      int j = i * 256 + t;
      int dd = j >> 8;
      int sb4 = (j & 255) * 4;
      const float4 v = *(const float4*)(V + (size_t)(d0 + dd) * (S_ * B_) + s0 * B_ + sb4);
      float vv[4] = {v.x, v.y, v.z, v.w};
#pragma unroll
      for (int k = 0; k < 4; k++) {
        int sb = sb4 + k;
        tile[(sb & 15) * 16 + dd][sb >> 4] = f2bf(vv[k]);  // row=b*16+dd, col=kv(0..63)
      }
    }
    __syncthreads();
    // write k-permuted A-frags: per (b, c32in{0,1}, lane l): 8 shorts
#pragma unroll
    for (int i = 0; i < 8; i++) {
      int j = i * 256 + t;                   // [0,2048)
      int b = j >> 7;
      int c32r = (j >> 6) & 1;
      int l = j & 63, g = l >> 4, ln = l & 15;
      const unsigned short* row = &tile[b * 16 + ln][c32r * 32];
      uint2 u0 = *(const uint2*)(row + g * 4);        // kv 4g..4g+3
      uint2 u1 = *(const uint2*)(row + 16 + g * 4);   // kv 16+4g..16+4g+3
      int c32 = (s0 >> 5) + c32r;
      uint4 o = make_uint4(u0.x, u0.y, u1.x, u1.y);
      *(uint4*)(Vt + (((size_t)(b * 64 + c32) * 4 + dblk) << 9) + l * 8) = o;
    }
  }
}

// ---------------------------------------------------------------------------
// attn: grid 512 = 16 b x 32 q-tiles (QT=64), 512 threads = 8 waves:
//       wave (qh = w>>2, ksw = w&3) = q-half (32 q) x kv-quarter (32 kv/tile).
//       Register diet for 4 waves/SIMD (the 2-wave cap was the VGPR cliff at
//       128): oacc 32, sacc 16, qf 16, kf 16, vf 16, pbf 8 (~115 peak).
//       Denominator via per-lane f32 adds (dacc 2 regs, g-reduce deferred to
//       epilogue LDS) instead of 4 ones-MFMAs -- saves 14 regs, 4 MFMA/tile,
//       and is MORE accurate (f32 exps vs bf16-rounded P).
//       S^T = K.Q^T on x32; PV on x32 via k-permuted V. No main-loop barriers.
// ---------------------------------------------------------------------------
__global__ __launch_bounds__(512, 4) void attn(const unsigned short* __restrict__ Qp,
                                               const unsigned short* __restrict__ Kp,
                                               const unsigned short* __restrict__ Vt,
                                               float* __restrict__ Ot) {
  __shared__ __align__(16) float red[2][2][32][68];   // [qh][p][q_local][d] 34816 B
  __shared__ float lred[2][4][4][32];                 // [qh][ksw][g][q_local] 4 KB

  const int tid = threadIdx.x;
  const int w = tid >> 6, l = tid & 63, g = l >> 4, ln = l & 15;
  const int qh = w >> 2, ksw = w & 3;
  const int b = blockIdx.x & 15;                // XCD-pinned batch
  const int q0 = (int)(blockIdx.x >> 4) * QT;

  const unsigned short* Qb = Qp + ((size_t)b << 17);   // b * 131072
  const unsigned short* Kb = Kp + ((size_t)b << 17);
  const unsigned short* Vb = Vt + ((size_t)b << 17);

  // per-wave/lane base pointers into the fragment-ordered buffers
  const unsigned short* Qw = Qb + (((size_t)((q0 >> 4) + qh * 2)) << 10) + l * 8;
  const unsigned short* Kw = Kb + ksw * 2048 + l * 8;
  const unsigned short* Vw = Vb + ksw * 2048 + l * 8;

  // Q^T B-frags (once per block): n=q_local=16nf+ln, k=d=32ks+8g+j
  short8 qf[2][2];
#pragma unroll
  for (int nf = 0; nf < 2; nf++)
#pragma unroll
    for (int ks = 0; ks < 2; ks++)
      qf[nf][ks] = *(const short8*)(Qw + nf * 1024 + ks * 512);

  // K frags tile 0 (wave-private kv slice rows)
  short8 kf[2][2];
#pragma unroll
  for (int mf = 0; mf < 2; mf++)
#pragma unroll
    for (int ks = 0; ks < 2; ks++)
      kf[mf][ks] = *(const short8*)(Kw + mf * 1024 + ks * 512);

  // V^T A-frags tile 0 (k-permuted layout): m=d=16mfd+ln, k-slot 8g+j
  short8 vf[4];
#pragma unroll
  for (int mfd = 0; mfd < 4; mfd++)
    vf[mfd] = *(const short8*)(Vw + mfd * 512);

  const floatx4 ZERO = {0.f, 0.f, 0.f, 0.f};
  floatx4 oacc[4][2];                           // [d=16mfd+4g+r][q_local=16nf+ln]
  float dacc[2] = {0.f, 0.f};                   // per-lane denom partials (per nf)
#pragma unroll
  for (int mfd = 0; mfd < 4; mfd++)
#pragma unroll
    for (int nf = 0; nf < 2; nf++) oacc[mfd][nf] = ZERO;

  for (int t = 0; t < 16; t++) {
    const int tn = ((t + 1) & 15) * 8192;       // next tile's frag offset (wraps)

    // ---- S^T[32 kv][32 q] = K . Q^T  (pre-scaled: sacc = s*SC2) ----
    floatx4 sacc[2][2];
    __builtin_amdgcn_s_setprio(1);
#pragma unroll
    for (int mf = 0; mf < 2; mf++)
#pragma unroll
      for (int nf = 0; nf < 2; nf++)
        sacc[mf][nf] = __builtin_amdgcn_mfma_f32_16x16x32_bf16(kf[mf][0], qf[nf][0],
                                                               ZERO, 0, 0, 0);
#pragma unroll
    for (int mf = 0; mf < 2; mf++)
#pragma unroll
      for (int nf = 0; nf < 2; nf++)
        sacc[mf][nf] = __builtin_amdgcn_mfma_f32_16x16x32_bf16(kf[mf][1], qf[nf][1],
                                                               sacc[mf][nf], 0, 0, 0);
    __builtin_amdgcn_s_setprio(0);

    // prefetch K frags for next tile (coalesced: 64 lanes x 16 B contiguous)
#pragma unroll
    for (int mf = 0; mf < 2; mf++)
#pragma unroll
      for (int ks = 0; ks < 2; ks++)
        kf[mf][ks] = *(const short8*)(Kw + tn + mf * 1024 + ks * 512);

    // ---- P = exp2(sacc): pack to bf16 (PV B-frag) + f32 denom partial ----
    short8 pbf[2];
#pragma unroll
    for (int nf = 0; nf < 2; nf++) {
      float e0 = __builtin_amdgcn_exp2f(sacc[0][nf][0]);
      float e1 = __builtin_amdgcn_exp2f(sacc[0][nf][1]);
      float e2 = __builtin_amdgcn_exp2f(sacc[0][nf][2]);
      float e3 = __builtin_amdgcn_exp2f(sacc[0][nf][3]);
      float e4 = __builtin_amdgcn_exp2f(sacc[1][nf][0]);
      float e5 = __builtin_amdgcn_exp2f(sacc[1][nf][1]);
      float e6 = __builtin_amdgcn_exp2f(sacc[1][nf][2]);
      float e7 = __builtin_amdgcn_exp2f(sacc[1][nf][3]);
      unsigned p00 = pk2(e0, e1), p01 = pk2(e2, e3);
      unsigned p10 = pk2(e4, e5), p11 = pk2(e6, e7);
      pbf[nf] = __builtin_bit_cast(short8, (uint4v){p00, p01, p10, p11});
      dacc[nf] += ((e0 + e1) + (e2 + e3)) + ((e4 + e5) + (e6 + e7));
    }

    __builtin_amdgcn_s_setprio(1);
    // ---- O^T += V^T . P^T over wave's 32 kv (single x32 per frag) ----
#pragma unroll
    for (int mfd = 0; mfd < 4; mfd++)
#pragma unroll
      for (int nf = 0; nf < 2; nf++)
        oacc[mfd][nf] = __builtin_amdgcn_mfma_f32_16x16x32_bf16(vf[mfd], pbf[nf],
                                                                oacc[mfd][nf], 0, 0, 0);
    __builtin_amdgcn_s_setprio(0);

    // prefetch V frags for next tile (coalesced: 64 lanes x 16 B contiguous)
#pragma unroll
    for (int mfd = 0; mfd < 4; mfd++)
      vf[mfd] = *(const short8*)(Vw + tn + mfd * 512);
  }

  // ---- epilogue: denom partials -> LDS; O reduce over ksw (2 barriers) ----
#pragma unroll
  for (int nf = 0; nf < 2; nf++)
    lred[qh][ksw][g][nf * 16 + ln] = dacc[nf];
  if (ksw < 2) {
#pragma unroll
    for (int mfd = 0; mfd < 4; mfd++)
#pragma unroll
      for (int nf = 0; nf < 2; nf++)
        *(floatx4*)(&red[qh][ksw][nf * 16 + ln][mfd * 16 + g * 4]) = oacc[mfd][nf];
  }
  __syncthreads();
  if (ksw >= 2) {
#pragma unroll
    for (int mfd = 0; mfd < 4; mfd++)
#pragma unroll
      for (int nf = 0; nf < 2; nf++) {
        float* p = &red[qh][ksw - 2][nf * 16 + ln][mfd * 16 + g * 4];
        *(floatx4*)p = *(const floatx4*)p + oacc[mfd][nf];
      }
  }
  __syncthreads();

  // wave (qh, dq=ksw) stores d-quarter [16dq,16dq+16) for its q-half.
  // lane: q_local = l&31, d-oct selected by l>>5.
  const int q = l & 31;
  const int dh = (l >> 5) * 8;
  float denom = 0.f;
#pragma unroll
  for (int kk = 0; kk < 4; kk++)
#pragma unroll
    for (int gg = 0; gg < 4; gg++) denom += lred[qh][kk][gg][q];
  const float linv = 1.0f / denom;
  const int dq = ksw;
  const int qcol = q0 + qh * 32 + q;
#pragma unroll
  for (int i = 0; i < 2; i++) {
    const int d = dq * 16 + dh + i * 4;
    floatx4 s = *(const floatx4*)(&red[qh][0][q][d]) +
                *(const floatx4*)(&red[qh][1][q][d]);
    s *= linv;
#pragma unroll
    for (int r = 0; r < 4; r++)
      Ot[(size_t)(b * D_ + d + r) * S_ + qcol] = s[r];
  }
}

// ---------------------------------------------------------------------------
// Unpack: Ot [B][D][S] f32 -> out [D][S][B] f32 (verified round 3).
// ---------------------------------------------------------------------------
__global__ __launch_bounds__(256) void unpack_o(const float* __restrict__ Ot,
                                                float* __restrict__ out) {
  const int d0 = (int)(blockIdx.x & 7) * 8;
  const int s0 = (int)(blockIdx.x >> 3) * 64;
  __shared__ float u[8 * 1024];
  const int t = threadIdx.x;
#pragma unroll
  for (int i = 0; i < 8; i++) {
    int j = i * 256 + t;
    int d = j >> 8, bb = (j >> 4) & 15, c = j & 15;
    float4 v = *(const float4*)(Ot + (size_t)(bb * D_ + d0 + d) * S_ + s0 + c * 4);
    float vv[4] = {v.x, v.y, v.z, v.w};
#pragma unroll
    for (int k = 0; k < 4; k++) {
      int si = c * 4 + k;
      int W = si * 16 + bb;
      int Wp = W ^ ((si & 15) << 2);
      u[d * 1024 + Wp] = vv[k];
    }
  }
  __syncthreads();
#pragma unroll
  for (int i = 0; i < 8; i++) {
    int j = i * 256 + t;
    int d = j >> 8, c2 = j & 255;
    int G = c2 ^ ((c2 >> 2) & 15);
    float4 v = *(const float4*)(&u[d * 1024 + G * 4]);
    *(float4*)(out + (size_t)(d0 + d) * (S_ * B_) + s0 * B_ + c2 * 4) = v;
  }
}

// ---------------------------------------------------------------------------
extern "C" void kernel_launch(void* const* d_in, const int* in_sizes, int n_in,
                              void* d_out, int out_size, void* d_ws, size_t ws_size,
                              hipStream_t stream) {
  const float* Q = (const float*)d_in[0];    // f32 [D][S][B]
  const float* K = (const float*)d_in[1];
  const float* V = (const float*)d_in[2];
  float* out = (float*)d_out;                // f32 [D][S][B]
  char* ws = (char*)d_ws;
  unsigned short* Qp = (unsigned short*)(ws);                  // 4 MB bf16, frag-ordered
  unsigned short* Kp = (unsigned short*)(ws + (4u << 20));     // 4 MB bf16, frag-ordered, pre-scaled
  unsigned short* Vt = (unsigned short*)(ws + (8u << 20));     // 4 MB bf16, k-permuted V^T
  float* Ot = (float*)(ws + (12u << 20));                      // 8 MB f32  [B][D][S]

  hipLaunchKernelGGL(pack_all, dim3(384), dim3(256), 0, stream, Q, K, V, Qp, Kp, Vt);
  hipLaunchKernelGGL(attn, dim3(512), dim3(512), 0, stream, Qp, Kp, Vt, Ot);
  hipLaunchKernelGGL(unpack_o, dim3(256), dim3(256), 0, stream, Ot, out);
}

// Round 11
// 101.611 us; speedup vs baseline: 1.0478x; 1.0478x over previous
//
#include <hip/hip_runtime.h>
#include <hip/hip_bf16.h>

#define D_ 64
#define S_ 2048
#define B_ 16
#define QT 64
#define KVT 128

typedef short short8 __attribute__((ext_vector_type(8)));
typedef float floatx4 __attribute__((ext_vector_type(4)));
typedef unsigned uint4v __attribute__((ext_vector_type(4)));

// exp(s/sqrt(2048)) == exp2(s * SC2); SC2 is pre-folded into the K pack.
#define SC2 (1.4426950408889634f / 45.254833995939045f)

__device__ __forceinline__ unsigned short f2bf(float f) {
  unsigned u = __builtin_bit_cast(unsigned, f);
  u += 0x7fffu + ((u >> 16) & 1u);   // round-to-nearest-even
  return (unsigned short)(u >> 16);
}

// two f32 -> packed bf16x2 (RNE), compiler-blessed path (emits
// v_cvt_pk_bf16_f32). __hip_bfloat162 is not trivially copyable -> memcpy.
__device__ __forceinline__ unsigned pk2(float a, float b) {
  __hip_bfloat162 h = __float22bfloat162_rn(float2{a, b});
  unsigned r;
  __builtin_memcpy(&r, &h, sizeof(r));
  return r;
}

// ---------------------------------------------------------------------------
// FRAGMENT-ORDERED layouts (so attn's loads are lane-contiguous):
//   Q/K: per b, 128 row-tiles (16 rows x 64 d). Element (row,d):
//        rb=row>>4, ln=row&15, ks=d>>5, g=(d>>3)&3, j=d&7
//        addr = (b*128+rb)*1024 + ks*512 + (g*16+ln)*8 + j
//   V (k-PERMUTED for x32 PV): per b, 64 kv-chunks (32 kv) x 4 dblk.
//        Lane l=(g,ln), elem e: d = dblk*16+ln, kv = c32*32 + perm(g,e),
//        perm(g,e) = e<4 ? 4g+e : 16+4g+(e-4)
//        addr = ((b*64+c32)*4+dblk)*512 + l*8 + e
// ---------------------------------------------------------------------------
__global__ __launch_bounds__(256) void pack_all(const float* __restrict__ Q,
                                                const float* __restrict__ K,
                                                const float* __restrict__ V,
                                                unsigned short* __restrict__ Qp,
                                                unsigned short* __restrict__ Kp,
                                                unsigned short* __restrict__ Vt) {
  __shared__ __align__(16) unsigned short tile[256][72];
  const int t = threadIdx.x;
  const int bid = blockIdx.x;
  if (bid < 256) {
    const bool isK = bid >= 128;
    const float* src = isK ? K : Q;
    unsigned short* dst = isK ? Kp : Qp;
    const float scale = isK ? SC2 : 1.0f;
    const int rb = bid & 127;
    const int s0 = rb * 16;
#pragma unroll
    for (int i = 0; i < 16; i++) {
      int j = i * 256 + t;
      int d = j >> 6;
      int sb4 = (j & 63) * 4;
      const float4 v = *(const float4*)(src + (size_t)d * (S_ * B_) + s0 * B_ + sb4);
      float vv[4] = {v.x, v.y, v.z, v.w};
#pragma unroll
      for (int k = 0; k < 4; k++) {
        int sb = sb4 + k;                    // si = sb>>4, b = sb&15
        tile[(sb & 15) * 16 + (sb >> 4)][d] = f2bf(vv[k] * scale);
      }
    }
    __syncthreads();
#pragma unroll
    for (int i = 0; i < 8; i++) {
      int j = i * 256 + t;
      int r = j >> 3, c = j & 7;
      int b = r >> 4, si = r & 15;
      uint4 v = *(const uint4*)(&tile[r][c * 8]);
      // frag order: ks=c>>2, g=c&3, ln=si, j=0..7 contiguous -> one uint4
      *(uint4*)(dst + (((size_t)(b * 128 + rb)) << 10) + ((c >> 2) << 9) +
                (((c & 3) * 16 + si) << 3)) = v;
    }
  } else {
    const int vb = bid - 256;
    const int s0 = (vb & 31) * 64;           // 64 kv per block
    const int d0 = (vb >> 5) * 16;
    const int dblk = vb >> 5;
#pragma unroll
    for (int i = 0; i < 16; i++) {
      int j = i * 256 + t;
      int dd = j >> 8;
      int sb4 = (j & 255) * 4;
      const float4 v = *(const float4*)(V + (size_t)(d0 + dd) * (S_ * B_) + s0 * B_ + sb4);
      float vv[4] = {v.x, v.y, v.z, v.w};
#pragma unroll
      for (int k = 0; k < 4; k++) {
        int sb = sb4 + k;
        tile[(sb & 15) * 16 + dd][sb >> 4] = f2bf(vv[k]);  // row=b*16+dd, col=kv(0..63)
      }
    }
    __syncthreads();
    // write k-permuted A-frags: per (b, c32in{0,1}, lane l): 8 shorts
#pragma unroll
    for (int i = 0; i < 8; i++) {
      int j = i * 256 + t;                   // [0,2048)
      int b = j >> 7;
      int c32r = (j >> 6) & 1;
      int l = j & 63, g = l >> 4, ln = l & 15;
      const unsigned short* row = &tile[b * 16 + ln][c32r * 32];
      uint2 u0 = *(const uint2*)(row + g * 4);        // kv 4g..4g+3
      uint2 u1 = *(const uint2*)(row + 16 + g * 4);   // kv 16+4g..16+4g+3
      int c32 = (s0 >> 5) + c32r;
      uint4 o = make_uint4(u0.x, u0.y, u1.x, u1.y);
      *(uint4*)(Vt + (((size_t)(b * 64 + c32) * 4 + dblk) << 9) + l * 8) = o;
    }
  }
}

// ---------------------------------------------------------------------------
// attn: round-9 structure (grid 512 = 16 b x 32 q-tiles, 4 waves/block, no
//       main-loop barriers) SOFTWARE-PIPELINED across tiles within the wave:
//       QK(t+1) is issued BEFORE exp/pack(t) + PV(t), so the matrix pipe
//       drains QK(t+1) while the trans/VALU pipes run the softmax of tile t
//       (QK(t+1) has no data dep on tile t's softmax). sacc double-buffered
//       (ping-pong via named buffers, compile-time indexed); K prefetch moved
//       one tile earlier. Numerically identical to round 9 (same ops, same
//       accumulation order; only issue order changes).
// ---------------------------------------------------------------------------
__global__ __launch_bounds__(256, 2) void attn(const unsigned short* __restrict__ Qp,
                                               const unsigned short* __restrict__ Kp,
                                               const unsigned short* __restrict__ Vt,
                                               float* __restrict__ Ot) {
  // red: [4 waves][64 q][68 d] f32 = 69632 B; lred 1 KB.
  __shared__ __align__(16) char smem_[69632 + 1024];
  float* red = (float*)smem_;
  float* lred = (float*)(smem_ + 69632);

  const int tid = threadIdx.x;
  const int w = tid >> 6, l = tid & 63, g = l >> 4, ln = l & 15;
  const int b = blockIdx.x & 15;                // XCD-pinned batch
  const int q0 = (int)(blockIdx.x >> 4) * QT;

  const unsigned short* Qb = Qp + ((size_t)b << 17);   // b * 131072
  const unsigned short* Kb = Kp + ((size_t)b << 17);
  const unsigned short* Vb = Vt + ((size_t)b << 17);

  // per-wave/lane base pointers into the fragment-ordered buffers
  const unsigned short* Qw = Qb + (((size_t)(q0 >> 4)) << 10) + l * 8;
  const unsigned short* Kw = Kb + w * 2048 + l * 8;    // wave's 2 row-tiles/128-kv
  const unsigned short* Vw = Vb + w * 2048 + l * 8;    // wave's c32 (=t*4+w) x 4 dblk

  // Q^T B-frags (once per block): n=q=16nf+ln, k=d=32ks+8g+j
  short8 qf[4][2];
#pragma unroll
  for (int nf = 0; nf < 4; nf++)
#pragma unroll
    for (int ks = 0; ks < 2; ks++)
      qf[nf][ks] = *(const short8*)(Qw + nf * 1024 + ks * 512);

  // K frags (holds the NEXT tile to be QK'd); start with tile 0
  short8 kf[2][2];
#pragma unroll
  for (int mf = 0; mf < 2; mf++)
#pragma unroll
    for (int ks = 0; ks < 2; ks++)
      kf[mf][ks] = *(const short8*)(Kw + mf * 1024 + ks * 512);

  // V^T A-frags tile 0 (k-permuted layout): m=d=16mfd+ln, k-slot 8g+j
  short8 vf[4];
#pragma unroll
  for (int mfd = 0; mfd < 4; mfd++)
    vf[mfd] = *(const short8*)(Vw + mfd * 512);

  const short8 ones8 = {(short)0x3F80, (short)0x3F80, (short)0x3F80, (short)0x3F80,
                        (short)0x3F80, (short)0x3F80, (short)0x3F80, (short)0x3F80};
  const floatx4 ZERO = {0.f, 0.f, 0.f, 0.f};
  floatx4 oacc[4][4];                           // [d=16mfd+4g+r][q=16nf+ln]
  floatx4 dacc[4];                              // denominator partials (rows equal)
#pragma unroll
  for (int mfd = 0; mfd < 4; mfd++)
#pragma unroll
    for (int nf = 0; nf < 4; nf++) oacc[mfd][nf] = ZERO;
#pragma unroll
  for (int nf = 0; nf < 4; nf++) dacc[nf] = ZERO;

  // sacc double buffers (ping-pong, compile-time indexed via lambda params)
  floatx4 sA[2][4], sB[2][4];

  // ---- prologue: QK(tile 0) -> sA; then load kf <- tile 1 ----
  __builtin_amdgcn_s_setprio(1);
#pragma unroll
  for (int mf = 0; mf < 2; mf++)
#pragma unroll
    for (int nf = 0; nf < 4; nf++)
      sA[mf][nf] = __builtin_amdgcn_mfma_f32_16x16x32_bf16(kf[mf][0], qf[nf][0],
                                                           ZERO, 0, 0, 0);
#pragma unroll
  for (int mf = 0; mf < 2; mf++)
#pragma unroll
    for (int nf = 0; nf < 4; nf++)
      sA[mf][nf] = __builtin_amdgcn_mfma_f32_16x16x32_bf16(kf[mf][1], qf[nf][1],
                                                           sA[mf][nf], 0, 0, 0);
  __builtin_amdgcn_s_setprio(0);
#pragma unroll
  for (int mf = 0; mf < 2; mf++)
#pragma unroll
    for (int ks = 0; ks < 2; ks++)
      kf[mf][ks] = *(const short8*)(Kw + 8192 + mf * 1024 + ks * 512);

  // step(cur, nxt, t): QK(t+1)->nxt (kf) | kf<-t+2 | softmax(cur=tile t) |
  //                    denom+PV(tile t, vf) | vf<-t+1
  auto step = [&](floatx4 (&cur)[2][4], floatx4 (&nxt)[2][4], int t)
      __attribute__((always_inline)) {
    const int tn1 = ((t + 1) & 15) * 8192;
    const int tn2 = ((t + 2) & 15) * 8192;

    // ---- QK(t+1) -> nxt (independent of tile t's softmax; fills the
    //      matrix pipe while the VALU/trans work below issues) ----
    __builtin_amdgcn_s_setprio(1);
#pragma unroll
    for (int mf = 0; mf < 2; mf++)
#pragma unroll
      for (int nf = 0; nf < 4; nf++)
        nxt[mf][nf] = __builtin_amdgcn_mfma_f32_16x16x32_bf16(kf[mf][0], qf[nf][0],
                                                              ZERO, 0, 0, 0);
#pragma unroll
    for (int mf = 0; mf < 2; mf++)
#pragma unroll
      for (int nf = 0; nf < 4; nf++)
        nxt[mf][nf] = __builtin_amdgcn_mfma_f32_16x16x32_bf16(kf[mf][1], qf[nf][1],
                                                              nxt[mf][nf], 0, 0, 0);
    __builtin_amdgcn_s_setprio(0);

    // prefetch kf <- tile t+2 (consumed by next step's QK)
#pragma unroll
    for (int mf = 0; mf < 2; mf++)
#pragma unroll
      for (int ks = 0; ks < 2; ks++)
        kf[mf][ks] = *(const short8*)(Kw + tn2 + mf * 1024 + ks * 512);

    // ---- P = exp2(cur) -> packed bf16 (PV B-frag = concat of chunk C-frags)
    short8 pbf[4];
#pragma unroll
    for (int nf = 0; nf < 4; nf++) {
      unsigned p00 = pk2(__builtin_amdgcn_exp2f(cur[0][nf][0]),
                         __builtin_amdgcn_exp2f(cur[0][nf][1]));
      unsigned p01 = pk2(__builtin_amdgcn_exp2f(cur[0][nf][2]),
                         __builtin_amdgcn_exp2f(cur[0][nf][3]));
      unsigned p10 = pk2(__builtin_amdgcn_exp2f(cur[1][nf][0]),
                         __builtin_amdgcn_exp2f(cur[1][nf][1]));
      unsigned p11 = pk2(__builtin_amdgcn_exp2f(cur[1][nf][2]),
                         __builtin_amdgcn_exp2f(cur[1][nf][3]));
      pbf[nf] = __builtin_bit_cast(short8, (uint4v){p00, p01, p10, p11});
    }

    __builtin_amdgcn_s_setprio(1);
    // ---- denominator: ones-row x32 MFMA (colsum of P over 32 kv) ----
#pragma unroll
    for (int nf = 0; nf < 4; nf++)
      dacc[nf] = __builtin_amdgcn_mfma_f32_16x16x32_bf16(ones8, pbf[nf], dacc[nf], 0, 0, 0);

    // ---- O^T += V^T . P^T over wave's 32 kv (single x32 per frag) ----
#pragma unroll
    for (int mfd = 0; mfd < 4; mfd++)
#pragma unroll
      for (int nf = 0; nf < 4; nf++)
        oacc[mfd][nf] = __builtin_amdgcn_mfma_f32_16x16x32_bf16(vf[mfd], pbf[nf],
                                                                oacc[mfd][nf], 0, 0, 0);
    __builtin_amdgcn_s_setprio(0);

    // prefetch vf <- tile t+1 (consumed by next step's PV)
#pragma unroll
    for (int mfd = 0; mfd < 4; mfd++)
      vf[mfd] = *(const short8*)(Vw + tn1 + mfd * 512);
  };

#pragma unroll 1
  for (int t = 0; t < 16; t += 2) {
    step(sA, sB, t);
    step(sB, sA, t + 1);
  }

  // ---- cross-wave reduction: O = sum_w O_w, denom = sum_w dacc ----
  if (g == 0) {
#pragma unroll
    for (int nf = 0; nf < 4; nf++) lred[w * 64 + nf * 16 + ln] = dacc[nf][0];
  }
#pragma unroll
  for (int mfd = 0; mfd < 4; mfd++)
#pragma unroll
    for (int nf = 0; nf < 4; nf++)
      *(floatx4*)(&red[w * 4352 + (nf * 16 + ln) * 68 + mfd * 16 + g * 4]) = oacc[mfd][nf];
  __syncthreads();

  // wave w reduces+stores d-quarter [16w,16w+16) for all 64 q; lane l = q
  const int q = l;
  const float denom = lred[q] + lred[64 + q] + lred[128 + q] + lred[192 + q];
  const float linv = 1.0f / denom;
#pragma unroll
  for (int i = 0; i < 4; i++) {
    floatx4 s = (floatx4){0.f, 0.f, 0.f, 0.f};
#pragma unroll
    for (int w2 = 0; w2 < 4; w2++)
      s += *(const floatx4*)(&red[w2 * 4352 + q * 68 + w * 16 + i * 4]);
    s *= linv;
#pragma unroll
    for (int r = 0; r < 4; r++)
      Ot[(size_t)(b * D_ + w * 16 + i * 4 + r) * S_ + q0 + q] = s[r];
  }
}

// ---------------------------------------------------------------------------
// Unpack: Ot [B][D][S] f32 -> out [D][S][B] f32 (verified round 3).
// ---------------------------------------------------------------------------
__global__ __launch_bounds__(256) void unpack_o(const float* __restrict__ Ot,
                                                float* __restrict__ out) {
  const int d0 = (int)(blockIdx.x & 7) * 8;
  const int s0 = (int)(blockIdx.x >> 3) * 64;
  __shared__ float u[8 * 1024];
  const int t = threadIdx.x;
#pragma unroll
  for (int i = 0; i < 8; i++) {
    int j = i * 256 + t;
    int d = j >> 8, bb = (j >> 4) & 15, c = j & 15;
    float4 v = *(const float4*)(Ot + (size_t)(bb * D_ + d0 + d) * S_ + s0 + c * 4);
    float vv[4] = {v.x, v.y, v.z, v.w};
#pragma unroll
    for (int k = 0; k < 4; k++) {
      int si = c * 4 + k;
      int W = si * 16 + bb;
      int Wp = W ^ ((si & 15) << 2);
      u[d * 1024 + Wp] = vv[k];
    }
  }
  __syncthreads();
#pragma unroll
  for (int i = 0; i < 8; i++) {
    int j = i * 256 + t;
    int d = j >> 8, c2 = j & 255;
    int G = c2 ^ ((c2 >> 2) & 15);
    float4 v = *(const float4*)(&u[d * 1024 + G * 4]);
    *(float4*)(out + (size_t)(d0 + d) * (S_ * B_) + s0 * B_ + c2 * 4) = v;
  }
}

// ---------------------------------------------------------------------------
extern "C" void kernel_launch(void* const* d_in, const int* in_sizes, int n_in,
                              void* d_out, int out_size, void* d_ws, size_t ws_size,
                              hipStream_t stream) {
  const float* Q = (const float*)d_in[0];    // f32 [D][S][B]
  const float* K = (const float*)d_in[1];
  const float* V = (const float*)d_in[2];
  float* out = (float*)d_out;                // f32 [D][S][B]
  char* ws = (char*)d_ws;
  unsigned short* Qp = (unsigned short*)(ws);                  // 4 MB bf16, frag-ordered
  unsigned short* Kp = (unsigned short*)(ws + (4u << 20));     // 4 MB bf16, frag-ordered, pre-scaled
  unsigned short* Vt = (unsigned short*)(ws + (8u << 20));     // 4 MB bf16, k-permuted V^T
  float* Ot = (float*)(ws + (12u << 20));                      // 8 MB f32  [B][D][S]

  hipLaunchKernelGGL(pack_all, dim3(384), dim3(256), 0, stream, Q, K, V, Qp, Kp, Vt);
  hipLaunchKernelGGL(attn, dim3(512), dim3(256), 0, stream, Qp, Kp, Vt, Ot);
  hipLaunchKernelGGL(unpack_o, dim3(256), dim3(256), 0, stream, Ot, out);
}

// Round 12
// 100.439 us; speedup vs baseline: 1.0600x; 1.0117x over previous
//
#include <hip/hip_runtime.h>

#define D_ 64
#define S_ 2048
#define B_ 16
#define QT 64
#define KVT 128

typedef short short8 __attribute__((ext_vector_type(8)));
typedef float floatx4 __attribute__((ext_vector_type(4)));
typedef unsigned uint2v __attribute__((ext_vector_type(2)));
typedef unsigned uint4v __attribute__((ext_vector_type(4)));

// exp(s/sqrt(2048)) == exp2(s * SC2); SC2 is pre-folded into the K pack.
#define SC2 (1.4426950408889634f / 45.254833995939045f)

__device__ __forceinline__ unsigned short f2bf(float f) {
  unsigned u = __builtin_bit_cast(unsigned, f);
  u += 0x7fffu + ((u >> 16) & 1u);   // round-to-nearest-even
  return (unsigned short)(u >> 16);
}

// ---------------------------------------------------------------------------
// FRAGMENT-ORDERED layouts (so attn's loads are lane-contiguous):
//   Q/K: per b, 128 row-tiles (16 rows x 64 d). Element (row,d):
//        rb=row>>4, ln=row&15, ks=d>>5, g=(d>>3)&3, j=d&7
//        addr = (b*128+rb)*1024 + ks*512 + (g*16+ln)*8 + j
//   V (k-PERMUTED for x32 PV): per b, 64 kv-chunks (32 kv) x 4 dblk.
//        Lane l=(g,ln), elem e: d = dblk*16+ln, kv = c32*32 + perm(g,e),
//        perm(g,e) = e<4 ? 4g+e : 16+4g+(e-4)
//        addr = ((b*64+c32)*4+dblk)*512 + l*8 + e
//        This matches the PV B-frag built from two packed QK C-frags
//        (k-slot 8g+j == kv perm(g,j) on BOTH operands -> result invariant).
// ---------------------------------------------------------------------------
__global__ __launch_bounds__(256) void pack_all(const float* __restrict__ Q,
                                                const float* __restrict__ K,
                                                const float* __restrict__ V,
                                                unsigned short* __restrict__ Qp,
                                                unsigned short* __restrict__ Kp,
                                                unsigned short* __restrict__ Vt) {
  __shared__ __align__(16) unsigned short tile[256][72];
  const int t = threadIdx.x;
  const int bid = blockIdx.x;
  if (bid < 256) {
    const bool isK = bid >= 128;
    const float* src = isK ? K : Q;
    unsigned short* dst = isK ? Kp : Qp;
    const float scale = isK ? SC2 : 1.0f;
    const int rb = bid & 127;
    const int s0 = rb * 16;
#pragma unroll
    for (int i = 0; i < 16; i++) {
      int j = i * 256 + t;
      int d = j >> 6;
      int sb4 = (j & 63) * 4;
      const float4 v = *(const float4*)(src + (size_t)d * (S_ * B_) + s0 * B_ + sb4);
      float vv[4] = {v.x, v.y, v.z, v.w};
#pragma unroll
      for (int k = 0; k < 4; k++) {
        int sb = sb4 + k;                    // si = sb>>4, b = sb&15
        tile[(sb & 15) * 16 + (sb >> 4)][d] = f2bf(vv[k] * scale);
      }
    }
    __syncthreads();
#pragma unroll
    for (int i = 0; i < 8; i++) {
      int j = i * 256 + t;
      int r = j >> 3, c = j & 7;
      int b = r >> 4, si = r & 15;
      uint4 v = *(const uint4*)(&tile[r][c * 8]);
      // frag order: ks=c>>2, g=c&3, ln=si, j=0..7 contiguous -> one uint4
      *(uint4*)(dst + (((size_t)(b * 128 + rb)) << 10) + ((c >> 2) << 9) +
                (((c & 3) * 16 + si) << 3)) = v;
    }
  } else {
    const int vb = bid - 256;
    const int s0 = (vb & 31) * 64;           // 64 kv per block
    const int d0 = (vb >> 5) * 16;
    const int dblk = vb >> 5;
#pragma unroll
    for (int i = 0; i < 16; i++) {
      int j = i * 256 + t;
      int dd = j >> 8;
      int sb4 = (j & 255) * 4;
      const float4 v = *(const float4*)(V + (size_t)(d0 + dd) * (S_ * B_) + s0 * B_ + sb4);
      float vv[4] = {v.x, v.y, v.z, v.w};
#pragma unroll
      for (int k = 0; k < 4; k++) {
        int sb = sb4 + k;
        tile[(sb & 15) * 16 + dd][sb >> 4] = f2bf(vv[k]);  // row=b*16+dd, col=kv(0..63)
      }
    }
    __syncthreads();
    // write k-permuted A-frags: per (b, c32in{0,1}, lane l): 8 shorts
#pragma unroll
    for (int i = 0; i < 8; i++) {
      int j = i * 256 + t;                   // [0,2048)
      int b = j >> 7;
      int c32r = (j >> 6) & 1;
      int l = j & 63, g = l >> 4, ln = l & 15;
      const unsigned short* row = &tile[b * 16 + ln][c32r * 32];
      uint2 u0 = *(const uint2*)(row + g * 4);        // kv 4g..4g+3
      uint2 u1 = *(const uint2*)(row + 16 + g * 4);   // kv 16+4g..16+4g+3
      int c32 = (s0 >> 5) + c32r;
      uint4 o = make_uint4(u0.x, u0.y, u1.x, u1.y);
      *(uint4*)(Vt + (((size_t)(b * 64 + c32) * 4 + dblk) << 9) + l * 8) = o;
    }
  }
}

// ---------------------------------------------------------------------------
// attn: S^T = K.Q^T (16x16x32, frag-ordered lane-contiguous global loads);
//       P packed in-register; PV + denominator ALSO on native 16x16x32 via
//       k-permutation (B-frag = concat of two packed C-frags, V pre-permuted
//       to match). O^T_w = V^T . P^T over wave-private 32-kv slices; one LDS
//       reduction. NO barriers in the main loop.
//       CHAMPION (round 5, 100.0 us). Falsified levers (each a clean A/B):
//       occupancy (r7/r10), L2 traffic halving (r7), VALU trim (r9),
//       source-level software pipelining (r11 — compiler already pipelines).
// ---------------------------------------------------------------------------
__global__ __launch_bounds__(256, 2) void attn(const unsigned short* __restrict__ Qp,
                                               const unsigned short* __restrict__ Kp,
                                               const unsigned short* __restrict__ Vt,
                                               float* __restrict__ Ot) {
  // red: [4 waves][64 q][68 d] f32 = 69632 B; lred 1 KB.
  __shared__ __align__(16) char smem_[69632 + 1024];
  float* red = (float*)smem_;
  float* lred = (float*)(smem_ + 69632);

  const int tid = threadIdx.x;
  const int w = tid >> 6, l = tid & 63, g = l >> 4, ln = l & 15;
  const int b = blockIdx.x & 15;                // XCD-pinned batch
  const int q0 = (int)(blockIdx.x >> 4) * QT;

  const unsigned short* Qb = Qp + ((size_t)b << 17);   // b * 131072
  const unsigned short* Kb = Kp + ((size_t)b << 17);
  const unsigned short* Vb = Vt + ((size_t)b << 17);

  // per-wave/lane base pointers into the fragment-ordered buffers
  const unsigned short* Qw = Qb + (((size_t)(q0 >> 4)) << 10) + l * 8;
  const unsigned short* Kw = Kb + w * 2048 + l * 8;    // wave's 2 row-tiles/128-kv
  const unsigned short* Vw = Vb + w * 2048 + l * 8;    // wave's c32 (=t*4+w) x 4 dblk

  // Q^T B-frags (once per block): n=q=16nf+ln, k=d=32ks+8g+j
  short8 qf[4][2];
#pragma unroll
  for (int nf = 0; nf < 4; nf++)
#pragma unroll
    for (int ks = 0; ks < 2; ks++)
      qf[nf][ks] = *(const short8*)(Qw + nf * 1024 + ks * 512);

  // K frags tile 0 (wave-private kv slice rows)
  short8 kf[2][2];
#pragma unroll
  for (int mf = 0; mf < 2; mf++)
#pragma unroll
    for (int ks = 0; ks < 2; ks++)
      kf[mf][ks] = *(const short8*)(Kw + mf * 1024 + ks * 512);

  // V^T A-frags tile 0 (k-permuted layout): m=d=16mfd+ln, k-slot 8g+j
  short8 vf[4];
#pragma unroll
  for (int mfd = 0; mfd < 4; mfd++)
    vf[mfd] = *(const short8*)(Vw + mfd * 512);

  const short8 ones8 = {(short)0x3F80, (short)0x3F80, (short)0x3F80, (short)0x3F80,
                        (short)0x3F80, (short)0x3F80, (short)0x3F80, (short)0x3F80};
  floatx4 oacc[4][4];                           // [d=16mfd+4g+r][q=16nf+ln]
  floatx4 dacc[4];                              // denominator partials (rows equal)
#pragma unroll
  for (int mfd = 0; mfd < 4; mfd++)
#pragma unroll
    for (int nf = 0; nf < 4; nf++) oacc[mfd][nf] = (floatx4){0.f, 0.f, 0.f, 0.f};
#pragma unroll
  for (int nf = 0; nf < 4; nf++) dacc[nf] = (floatx4){0.f, 0.f, 0.f, 0.f};

  for (int t = 0; t < 16; t++) {
    const int tn = ((t + 1) & 15) * 8192;       // next tile's frag offset (wraps)

    // ---- S^T[32 kv][64 q] = K . Q^T  (pre-scaled: sacc = s*SC2) ----
    floatx4 sacc[2][4];
#pragma unroll
    for (int mf = 0; mf < 2; mf++)
#pragma unroll
      for (int nf = 0; nf < 4; nf++) sacc[mf][nf] = (floatx4){0.f, 0.f, 0.f, 0.f};
    __builtin_amdgcn_s_setprio(1);
#pragma unroll
    for (int ks = 0; ks < 2; ks++)
#pragma unroll
      for (int mf = 0; mf < 2; mf++)
#pragma unroll
        for (int nf = 0; nf < 4; nf++)
          sacc[mf][nf] = __builtin_amdgcn_mfma_f32_16x16x32_bf16(kf[mf][ks], qf[nf][ks],
                                                                 sacc[mf][nf], 0, 0, 0);
    __builtin_amdgcn_s_setprio(0);

    // prefetch K frags for next tile (coalesced: 64 lanes x 16 B contiguous)
#pragma unroll
    for (int mf = 0; mf < 2; mf++)
#pragma unroll
      for (int ks = 0; ks < 2; ks++)
        kf[mf][ks] = *(const short8*)(Kw + tn + mf * 1024 + ks * 512);

    // ---- P = exp2(sacc), packed in-register; B-frag for x32 PV is the
    //      register-local concat of the two chunk C-frags (k-permuted) ----
    short8 pbf[4];
#pragma unroll
    for (int nf = 0; nf < 4; nf++) {
      uint2v pu[2];
#pragma unroll
      for (int mf = 0; mf < 2; mf++) {
        unsigned u0 = __builtin_bit_cast(unsigned, __builtin_amdgcn_exp2f(sacc[mf][nf][0])) + 0x8000u;
        unsigned u1 = __builtin_bit_cast(unsigned, __builtin_amdgcn_exp2f(sacc[mf][nf][1])) + 0x8000u;
        unsigned u2 = __builtin_bit_cast(unsigned, __builtin_amdgcn_exp2f(sacc[mf][nf][2])) + 0x8000u;
        unsigned u3 = __builtin_bit_cast(unsigned, __builtin_amdgcn_exp2f(sacc[mf][nf][3])) + 0x8000u;
        unsigned lo = __builtin_amdgcn_perm(u1, u0, 0x07060302u);  // [bf16(e0), bf16(e1)]
        unsigned hi = __builtin_amdgcn_perm(u3, u2, 0x07060302u);  // [bf16(e2), bf16(e3)]
        pu[mf] = (uint2v){lo, hi};
      }
      pbf[nf] = __builtin_bit_cast(short8, (uint4v){pu[0][0], pu[0][1], pu[1][0], pu[1][1]});
    }

    __builtin_amdgcn_s_setprio(1);
    // ---- denominator: ones-row x32 MFMA (colsum of P over 32 kv) ----
#pragma unroll
    for (int nf = 0; nf < 4; nf++)
      dacc[nf] = __builtin_amdgcn_mfma_f32_16x16x32_bf16(ones8, pbf[nf], dacc[nf], 0, 0, 0);

    // ---- O^T += V^T . P^T over wave's 32 kv (single x32 per frag) ----
#pragma unroll
    for (int mfd = 0; mfd < 4; mfd++)
#pragma unroll
      for (int nf = 0; nf < 4; nf++)
        oacc[mfd][nf] = __builtin_amdgcn_mfma_f32_16x16x32_bf16(vf[mfd], pbf[nf],
                                                                oacc[mfd][nf], 0, 0, 0);
    __builtin_amdgcn_s_setprio(0);

    // prefetch V frags for next tile (coalesced: 64 lanes x 16 B contiguous)
#pragma unroll
    for (int mfd = 0; mfd < 4; mfd++)
      vf[mfd] = *(const short8*)(Vw + tn + mfd * 512);
  }

  // ---- cross-wave reduction: O = sum_w O_w, denom = sum_w dacc ----
  if (g == 0) {
#pragma unroll
    for (int nf = 0; nf < 4; nf++) lred[w * 64 + nf * 16 + ln] = dacc[nf][0];
  }
#pragma unroll
  for (int mfd = 0; mfd < 4; mfd++)
#pragma unroll
    for (int nf = 0; nf < 4; nf++)
      *(floatx4*)(&red[w * 4352 + (nf * 16 + ln) * 68 + mfd * 16 + g * 4]) = oacc[mfd][nf];
  __syncthreads();

  // wave w reduces+stores d-quarter [16w,16w+16) for all 64 q; lane l = q
  const int q = l;
  const float denom = lred[q] + lred[64 + q] + lred[128 + q] + lred[192 + q];
  const float linv = 1.0f / denom;
#pragma unroll
  for (int i = 0; i < 4; i++) {
    floatx4 s = (floatx4){0.f, 0.f, 0.f, 0.f};
#pragma unroll
    for (int w2 = 0; w2 < 4; w2++)
      s += *(const floatx4*)(&red[w2 * 4352 + q * 68 + w * 16 + i * 4]);
    s *= linv;
#pragma unroll
    for (int r = 0; r < 4; r++)
      Ot[(size_t)(b * D_ + w * 16 + i * 4 + r) * S_ + q0 + q] = s[r];
  }
}

// ---------------------------------------------------------------------------
// Unpack: Ot [B][D][S] f32 -> out [D][S][B] f32 (verified round 3).
// ---------------------------------------------------------------------------
__global__ __launch_bounds__(256) void unpack_o(const float* __restrict__ Ot,
                                                float* __restrict__ out) {
  const int d0 = (int)(blockIdx.x & 7) * 8;
  const int s0 = (int)(blockIdx.x >> 3) * 64;
  __shared__ float u[8 * 1024];
  const int t = threadIdx.x;
#pragma unroll
  for (int i = 0; i < 8; i++) {
    int j = i * 256 + t;
    int d = j >> 8, bb = (j >> 4) & 15, c = j & 15;
    float4 v = *(const float4*)(Ot + (size_t)(bb * D_ + d0 + d) * S_ + s0 + c * 4);
    float vv[4] = {v.x, v.y, v.z, v.w};
#pragma unroll
    for (int k = 0; k < 4; k++) {
      int si = c * 4 + k;
      int W = si * 16 + bb;
      int Wp = W ^ ((si & 15) << 2);
      u[d * 1024 + Wp] = vv[k];
    }
  }
  __syncthreads();
#pragma unroll
  for (int i = 0; i < 8; i++) {
    int j = i * 256 + t;
    int d = j >> 8, c2 = j & 255;
    int G = c2 ^ ((c2 >> 2) & 15);
    float4 v = *(const float4*)(&u[d * 1024 + G * 4]);
    *(float4*)(out + (size_t)(d0 + d) * (S_ * B_) + s0 * B_ + c2 * 4) = v;
  }
}

// ---------------------------------------------------------------------------
extern "C" void kernel_launch(void* const* d_in, const int* in_sizes, int n_in,
                              void* d_out, int out_size, void* d_ws, size_t ws_size,
                              hipStream_t stream) {
  const float* Q = (const float*)d_in[0];    // f32 [D][S][B]
  const float* K = (const float*)d_in[1];
  const float* V = (const float*)d_in[2];
  float* out = (float*)d_out;                // f32 [D][S][B]
  char* ws = (char*)d_ws;
  unsigned short* Qp = (unsigned short*)(ws);                  // 4 MB bf16, frag-ordered
  unsigned short* Kp = (unsigned short*)(ws + (4u << 20));     // 4 MB bf16, frag-ordered, pre-scaled
  unsigned short* Vt = (unsigned short*)(ws + (8u << 20));     // 4 MB bf16, k-permuted V^T
  float* Ot = (float*)(ws + (12u << 20));                      // 8 MB f32  [B][D][S]

  hipLaunchKernelGGL(pack_all, dim3(384), dim3(256), 0, stream, Q, K, V, Qp, Kp, Vt);
  hipLaunchKernelGGL(attn, dim3(512), dim3(256), 0, stream, Qp, Kp, Vt, Ot);
  hipLaunchKernelGGL(unpack_o, dim3(256), dim3(256), 0, stream, Ot, out);
}